// Round 8
// baseline (441.709 us; speedup 1.0000x reference)
//
#include <hip/hip_runtime.h>
#include <hip/hip_bf16.h>
#include <hip/hip_fp16.h>

typedef unsigned short u16;
typedef unsigned int u32;
typedef __attribute__((ext_vector_type(8))) _Float16 f16x8;
typedef __attribute__((ext_vector_type(4))) float f32x4;

#define NEG 0.2f

__device__ __forceinline__ float bf2f(u16 u) {
    return __uint_as_float(((u32)u) << 16);
}
__device__ __forceinline__ u16 f2b(float f) {   // round-to-nearest-even f32->bf16
    u32 u = __float_as_uint(f);
    u32 r = (u + 0x7FFF + ((u >> 16) & 1)) >> 16;
    return (u16)r;
}
__device__ __forceinline__ u16 f2h(float f) {   // f32 -> f16 bits
    return __half_as_ushort(__float2half(f));
}
__device__ __forceinline__ float h2f(u16 u) {
    return __half2float(__ushort_as_half(u));
}
__device__ __forceinline__ float sigm(float x) {
    return 1.0f / (1.0f + __expf(-x));
}
__device__ __forceinline__ float ldin(const void* p, int idx, int flag) {
    if (flag) return ((const float*)p)[idx];
    return bf2f(((const u16*)p)[idx]);
}
__device__ __forceinline__ u16 ldin_h(const void* p, int idx, int flag) {  // -> f16 bits
    if (flag) return f2h(((const float*)p)[idx]);
    return f2h(bf2f(((const u16*)p)[idx]));
}

// ---------------- ws layout (bytes) ----------------
// flag    u32                        @ 0          (64)
// wiA     f16 [12][9][2][64][8]      @ 64         (221184)  i2h A-frags
// wfA     f16 [2][25][4][64][8]      @ 221248     (204800)  flowfeat A-frags
// wlA     f16 [2][25][64][8]         @ 426048     (51200)   flows A-frags
// wretA   f16 [12][26][64][8]        @ 477248     (319488)  ret A-frags
// biases  f32 [474]                  @ 796736     (2048)
// xph     f16 [8][96][96][128]       @ 798784     (18874368)  NHWC x||prev_h
// i2hT    f16 [8][96][96][192]       @ 19673152   (28311552)
// fT      f16 [8][96][96][32]        @ 47984704   (4718592)
// flows   f32 [8][26][96][96]        @ 52703296   (7667712)
// total: 60371008

#define WS_NEED 60371008u

// ---------------- K-1: dtype detect ----------------
__global__ void kdetect(const u16* __restrict__ x, u32* __restrict__ flag)
{
    __shared__ u32 mx[256];
    int t = threadIdx.x;
    u32 m = 0;
    for (int i = t; i < 8192; i += 256) {
        u32 e = ((u32)x[i] >> 7) & 0xFF;
        m = m > e ? m : e;
    }
    mx[t] = m;
    __syncthreads();
    for (int s = 128; s > 0; s >>= 1) {
        if (t < s) mx[t] = mx[t] > mx[t + s] ? mx[t] : mx[t + s];
        __syncthreads();
    }
    if (t == 0) flag[0] = (mx[0] > 0xC0) ? 1u : 0u;
}

// ---------------- K0a: weight repack -> MFMA A-fragments (f16) ----------------
__global__ void kprep(const void* __restrict__ w_i2h, const void* __restrict__ w_i2f,
                      const void* __restrict__ w_h2f, const void* __restrict__ w_fl,
                      const void* __restrict__ w_ret,
                      const void* __restrict__ b_i2h, const void* __restrict__ b_i2f,
                      const void* __restrict__ b_h2f, const void* __restrict__ b_fl,
                      const void* __restrict__ b_ret,
                      u16* __restrict__ wiA, u16* __restrict__ wfA,
                      u16* __restrict__ wlA, u16* __restrict__ wretA,
                      float* __restrict__ biases, const u32* __restrict__ flag)
{
    int flg = (int)flag[0];
    int i = blockIdx.x * 256 + threadIdx.x;
    // A-frag pattern: A[m=lane&15][k=(lane>>4)*8+j]  (validated R4)
    if (i < 110592) {                 // wiA [mt12][tap9][cib2][lane][j]
        int j = i & 7; int lane = (i >> 3) & 63; int rest = i >> 9;
        int cib = rest & 1; int rest2 = rest >> 1;
        int tap = rest2 % 9; int mt = rest2 / 9;
        int oc = mt * 16 + (lane & 15);
        int ci = cib * 32 + ((lane >> 4) << 3) + j;
        wiA[i] = ldin_h(w_i2h, (oc * 64 + ci) * 9 + tap, flg);
    }
    if (i < 102400) {                 // wfA [mt2][tap25][cib4][lane][j]
        int j = i & 7; int lane = (i >> 3) & 63; int rest = i >> 9;
        int cib = rest & 3; int rest2 = rest >> 2;
        int tap = rest2 % 25; int mt = rest2 / 25;
        int oc = mt * 16 + (lane & 15);
        int cip = cib * 32 + ((lane >> 4) << 3) + j;
        wfA[i] = (cip < 64) ? ldin_h(w_i2f, (oc * 64 + cip) * 25 + tap, flg)
                            : ldin_h(w_h2f, (oc * 64 + cip - 64) * 25 + tap, flg);
    }
    if (i < 25600) {                  // wlA [mt2][tap25][lane][j], oc>=26 -> 0
        int j = i & 7; int lane = (i >> 3) & 63; int rest = i >> 9;
        int tap = rest % 25; int mt = rest / 25;
        int oc = mt * 16 + (lane & 15);
        int ci = ((lane >> 4) << 3) + j;
        wlA[i] = (oc < 26) ? ldin_h(w_fl, (oc * 32 + ci) * 25 + tap, flg) : (u16)0;
    }
    if (i < 159744) {                 // wretA [mt12][ks26][lane][j]
        int j = i & 7; int l = (i >> 3) & 63; int rest = i >> 9;
        int ks = rest % 26; int mt = rest / 26;
        int o = mt * 16 + (l & 15);
        int k = ks * 32 + ((l >> 4) << 3) + j;
        wretA[i] = ldin_h(w_ret, o * 832 + k, flg);
    }
    if (i < 474) {
        float v;
        if (i < 192)      v = ldin(b_i2h, i, flg);
        else if (i < 224) v = ldin(b_i2f, i - 192, flg);
        else if (i < 256) v = ldin(b_h2f, i - 224, flg);
        else if (i < 282) v = ldin(b_fl, i - 256, flg);
        else              v = ldin(b_ret, i - 282, flg);
        biases[i] = v;
    }
}

// ---------------- K0b: x, prev_h (NCHW) -> xph NHWC f16 [B][H][W][128] ------
__global__ __launch_bounds__(256) void kxph(const void* __restrict__ x,
        const void* __restrict__ ph, u16* __restrict__ xph,
        const u32* __restrict__ flag)
{
    __shared__ u16 tile[64 * 97];
    int flg = (int)flag[0];
    int h = blockIdx.x, b = blockIdx.y;
    int t = threadIdx.x;
#pragma unroll 1
    for (int s = 0; s < 2; s++) {
        const void* src = s ? ph : x;
        for (int i = t; i < 6144; i += 256) {
            int c = i / 96, w = i % 96;
            tile[c * 97 + w] = ldin_h(src, ((b * 64 + c) * 96 + h) * 96 + w, flg);
        }
        __syncthreads();
        for (int i = t; i < 6144; i += 256) {
            int c = i & 63, w = i >> 6;
            xph[(((b * 96 + h) * 96 + w) << 7) + s * 64 + c] = tile[c * 97 + w];
        }
        __syncthreads();
    }
}

// ---------------- K1: merged i2h(3x3,64->192) + flowfeat(5x5,128->32) -------
// Block: 32 px x 4 rows, waves on rows, 2 N-tiles per wave. 576 blocks,
// b = blockIdx&7 -> per-XCD batch locality.
__global__ __launch_bounds__(256) void k_convs(const u16* __restrict__ xph,
        const u16* __restrict__ wiA, const u16* __restrict__ wfA,
        const float* __restrict__ biases,
        u16* __restrict__ i2hT, u16* __restrict__ fT)
{
    __shared__ __align__(16) u16 xl[8 * 36 * 136];   // 78336 B, pos-stride 136
    int id = blockIdx.x;
    int b = id & 7; int r = id >> 3;          // r in [0,72)
    int x0 = (r % 3) * 32, y0 = (r / 3) * 4;
    int t = threadIdx.x, lane = t & 63, wv = t >> 6;
    int n = lane & 15, quad = lane >> 4;

    // halo: 8 rows x 36 cols x 128 ch = 288 pos x 16 chunks(16B) = 4608 items
    for (int i = t; i < 4608; i += 256) {
        int co = i & 15; int pos = i >> 4; int xx = pos % 36; int yy = pos / 36;
        int gy = y0 + yy - 2, gx = x0 + xx - 2;
        uint4 v = make_uint4(0, 0, 0, 0);
        if (gy >= 0 && gy < 96 && gx >= 0 && gx < 96)
            v = *(const uint4*)&xph[((((b * 96 + gy) * 96 + gx)) << 7) + (co << 3)];
        *(uint4*)&xl[(yy * 36 + xx) * 136 + (co << 3)] = v;
    }
    __syncthreads();

    const f16x8* Af = (const f16x8*)wfA;
    const f16x8* Ai = (const f16x8*)wiA;

    // ---- flowfeat: halo offset (dy,dx) in [0,5)^2 ----
    {
        f32x4 f00 = {}, f01 = {}, f10 = {}, f11 = {};   // [mt][nt]
#pragma unroll 1
        for (int tap = 0; tap < 25; tap++) {
            int dy = tap / 5, dx = tap % 5;
            int rowb = ((wv + dy) * 36 + n + dx) * 136 + quad * 8;
#pragma unroll
            for (int cib = 0; cib < 4; cib++) {
                f16x8 b0 = *(const f16x8*)&xl[rowb + cib * 32];
                f16x8 b1 = *(const f16x8*)&xl[rowb + 16 * 136 + cib * 32];
                f16x8 a0 = Af[(tap * 4 + cib) * 64 + lane];
                f16x8 a1 = Af[((25 + tap) * 4 + cib) * 64 + lane];
                f00 = __builtin_amdgcn_mfma_f32_16x16x32_f16(a0, b0, f00, 0, 0, 0);
                f01 = __builtin_amdgcn_mfma_f32_16x16x32_f16(a0, b1, f01, 0, 0, 0);
                f10 = __builtin_amdgcn_mfma_f32_16x16x32_f16(a1, b0, f10, 0, 0, 0);
                f11 = __builtin_amdgcn_mfma_f32_16x16x32_f16(a1, b1, f11, 0, 0, 0);
            }
        }
#pragma unroll
        for (int nt = 0; nt < 2; nt++) {
            const f32x4& lo = nt ? f01 : f00;
            const f32x4& hi = nt ? f11 : f10;
            int base = (((b * 96 + y0 + wv) * 96 + x0 + nt * 16 + n)) * 32 + quad * 4;
            u16 p[4];
#pragma unroll
            for (int rr = 0; rr < 4; rr++) {
                int oc = quad * 4 + rr;
                float v = lo[rr] + biases[192 + oc] + biases[224 + oc];
                v = (v > 0.f) ? v : NEG * v;
                p[rr] = f2h(v);
            }
            *(uint2*)&fT[base] = make_uint2(p[0] | ((u32)p[1] << 16), p[2] | ((u32)p[3] << 16));
#pragma unroll
            for (int rr = 0; rr < 4; rr++) {
                int oc = 16 + quad * 4 + rr;
                float v = hi[rr] + biases[192 + oc] + biases[224 + oc];
                v = (v > 0.f) ? v : NEG * v;
                p[rr] = f2h(v);
            }
            *(uint2*)&fT[base + 16] = make_uint2(p[0] | ((u32)p[1] << 16), p[2] | ((u32)p[3] << 16));
        }
    }

    // ---- i2h: halo offset (+1,+1), ch 0..63, 2 passes of 6 M-tiles ----
#pragma unroll 1
    for (int pass = 0; pass < 2; pass++) {
        f32x4 acc[6][2] = {};
#pragma unroll
        for (int dy = 0; dy < 3; dy++)
#pragma unroll
            for (int dx = 0; dx < 3; dx++) {
                int tap = dy * 3 + dx;
                int rowb = ((wv + dy + 1) * 36 + n + dx + 1) * 136 + quad * 8;
#pragma unroll
                for (int cib = 0; cib < 2; cib++) {
                    f16x8 b0 = *(const f16x8*)&xl[rowb + cib * 32];
                    f16x8 b1 = *(const f16x8*)&xl[rowb + 16 * 136 + cib * 32];
#pragma unroll
                    for (int mi = 0; mi < 6; mi++) {
                        f16x8 a = Ai[(((pass * 6 + mi) * 9 + tap) * 2 + cib) * 64 + lane];
                        acc[mi][0] = __builtin_amdgcn_mfma_f32_16x16x32_f16(a, b0, acc[mi][0], 0, 0, 0);
                        acc[mi][1] = __builtin_amdgcn_mfma_f32_16x16x32_f16(a, b1, acc[mi][1], 0, 0, 0);
                    }
                }
            }
#pragma unroll
        for (int nt = 0; nt < 2; nt++) {
            int base = (((b * 96 + y0 + wv) * 96 + x0 + nt * 16 + n)) * 192 + quad * 4;
#pragma unroll
            for (int mi = 0; mi < 6; mi++) {
                int ocb = (pass * 6 + mi) * 16 + quad * 4;
                u16 p0 = f2h(acc[mi][nt][0] + biases[ocb + 0]);
                u16 p1 = f2h(acc[mi][nt][1] + biases[ocb + 1]);
                u16 p2 = f2h(acc[mi][nt][2] + biases[ocb + 2]);
                u16 p3 = f2h(acc[mi][nt][3] + biases[ocb + 3]);
                *(uint2*)&i2hT[base + (pass * 6 + mi) * 16] =
                    make_uint2(p0 | ((u32)p1 << 16), p2 | ((u32)p3 << 16));
            }
        }
    }
}

// ---------------- K3: flows 5x5 conv (32 -> 26) via MFMA, out NCHW f32 -------
__global__ __launch_bounds__(256) void k_flows(const u16* __restrict__ fT,
        const u16* __restrict__ wlA, const float* __restrict__ biases,
        float* __restrict__ flows)
{
    __shared__ __align__(16) u16 xl[8 * 20 * 40];   // 12800 B, x-stride 40
    int id = blockIdx.x;
    int b = id & 7; int r = id >> 3;          // r in [0,144)
    int x0 = (r % 6) * 16, y0 = (r / 6) * 4;
    int t = threadIdx.x, lane = t & 63, wv = t >> 6;
    int n = lane & 15, quad = lane >> 4;

    for (int i = t; i < 640; i += 256) {    // 160 pos x 4 chunks(16B)
        int co = i & 3; int pos = i >> 2; int xx = pos % 20; int yy = pos / 20;
        int gy = y0 + yy - 2, gx = x0 + xx - 2;
        uint4 v = make_uint4(0, 0, 0, 0);
        if (gy >= 0 && gy < 96 && gx >= 0 && gx < 96)
            v = *(const uint4*)&fT[((((b * 96 + gy) * 96 + gx)) << 5) + (co << 3)];
        *(uint4*)&xl[(yy * 20 + xx) * 40 + (co << 3)] = v;
    }
    __syncthreads();

    f32x4 acc0 = {}, acc1 = {};
    const f16x8* A = (const f16x8*)wlA;
#pragma unroll 1
    for (int tap = 0; tap < 25; tap++) {
        int dy = tap / 5, dx = tap % 5;
        f16x8 bb = *(const f16x8*)&xl[((wv + dy) * 20 + n + dx) * 40 + quad * 8];
        f16x8 a0 = A[tap * 64 + lane];
        f16x8 a1 = A[(25 + tap) * 64 + lane];
        acc0 = __builtin_amdgcn_mfma_f32_16x16x32_f16(a0, bb, acc0, 0, 0, 0);
        acc1 = __builtin_amdgcn_mfma_f32_16x16x32_f16(a1, bb, acc1, 0, 0, 0);
    }

    int pix = (y0 + wv) * 96 + x0 + n;
#pragma unroll
    for (int rr = 0; rr < 4; rr++) {
        int oc = quad * 4 + rr;
        flows[(b * 26 + oc) * 9216 + pix] = acc0[rr] + biases[256 + oc];
        int oc1 = 16 + quad * 4 + rr;
        if (oc1 < 26)
            flows[(b * 26 + oc1) * 9216 + pix] = acc1[rr] + biases[256 + oc1];
    }
}

// ---------------- K4: warp + 1x1 conv (MFMA) + gates (fused) ----------------
// LDS = wl only (53760 B) -> 3 blocks/CU. Gather: 8 ch/lane, 16B loads.
__global__ __launch_bounds__(256) void k_fused(const float* __restrict__ flows,
        const u16* __restrict__ xph, const u16* __restrict__ i2hT,
        const u16* __restrict__ wretA, const float* __restrict__ biases,
        void* __restrict__ out, const u32* __restrict__ flag)
{
    __shared__ __align__(16) u16 wl[32 * 840];   // warped [p][k] f16; aliased as hh[192][33] f32

    int flg = (int)flag[0];
    int id = blockIdx.x;
    int b = id & 7; int r = id >> 3;          // r in [0,288)
    int h = r / 3, w0 = (r % 3) * 32;
    int t = threadIdx.x;
    int lane = t & 63, wv = t >> 6;
    const float S = 96.f / 95.f;
    int hrow = h * 96 + w0;

    // phase A: bilinear gather -> wl[p][l*64+c], 8 channels per lane
#pragma unroll 1
    for (int it = 0; it < 13; it++) {
        int idx = t + 256 * it;          // 0..3327
        int sub = idx & 7;               // channel-group (8 ch)
        int pair = idx >> 3;             // 0..415
        int p = pair & 31, l = pair >> 5;
        float dx = flows[(b * 26 + 2 * l) * 9216 + hrow + p];
        float dy = flows[(b * 26 + 2 * l + 1) * 9216 + hrow + p];
        float px = ((float)(w0 + p) - dx) * S - 0.5f;
        float py = ((float)h - dy) * S - 0.5f;
        float fx = floorf(px), fy = floorf(py);
        int x0 = (int)fx, y0 = (int)fy;
        float wx = px - fx, wy = py - fy;
        bool xv0 = (x0 >= 0) & (x0 < 96);
        bool xv1 = (x0 >= -1) & (x0 < 95);
        bool yv0 = (y0 >= 0) & (y0 < 96);
        bool yv1 = (y0 >= -1) & (y0 < 95);
        int c0 = 64 + sub * 8;           // ph channels 64..127
        f16x8 v00 = {}, v10 = {}, v01 = {}, v11 = {};
        if (yv0) {
            const u16* rp = &xph[((b * 96 + y0) * 96 + x0) * 128 + c0];
            if (xv0) v00 = *(const f16x8*)rp;
            if (xv1) v10 = *(const f16x8*)(rp + 128);
        }
        if (yv1) {
            const u16* rp = &xph[((b * 96 + y0 + 1) * 96 + x0) * 128 + c0];
            if (xv0) v01 = *(const f16x8*)rp;
            if (xv1) v11 = *(const f16x8*)(rp + 128);
        }
        float w00 = (1.f - wx) * (1.f - wy), w10 = wx * (1.f - wy);
        float w01 = (1.f - wx) * wy,         w11 = wx * wy;
        u16 res[8];
#pragma unroll
        for (int j = 0; j < 8; j++) {
            float v = w00 * (float)v00[j] + w10 * (float)v10[j]
                    + w01 * (float)v01[j] + w11 * (float)v11[j];
            res[j] = f2h(v);
        }
        *(uint4*)&wl[p * 840 + l * 64 + sub * 8] = *(const uint4*)res;
    }
    __syncthreads();

    // phase B: MFMA GEMM h2h[192][32] = wret[192][832] x warped[832][32]
    int n = lane & 15, q = lane >> 4;
    int mt0 = wv * 3;
    f32x4 acc[3][2] = {};
    f16x8 aC[3], aN[3];
    const f16x8* Ap = (const f16x8*)wretA;
#pragma unroll
    for (int mi = 0; mi < 3; mi++)
        aC[mi] = Ap[((mt0 + mi) * 26 + 0) * 64 + lane];
#pragma unroll 1
    for (int ks = 0; ks < 26; ks++) {
        if (ks < 25) {
#pragma unroll
            for (int mi = 0; mi < 3; mi++)
                aN[mi] = Ap[((mt0 + mi) * 26 + ks + 1) * 64 + lane];
        }
        f16x8 b0 = *(const f16x8*)&wl[n * 840 + ks * 32 + q * 8];
        f16x8 b1 = *(const f16x8*)&wl[(16 + n) * 840 + ks * 32 + q * 8];
#pragma unroll
        for (int mi = 0; mi < 3; mi++) {
            acc[mi][0] = __builtin_amdgcn_mfma_f32_16x16x32_f16(aC[mi], b0, acc[mi][0], 0, 0, 0);
            acc[mi][1] = __builtin_amdgcn_mfma_f32_16x16x32_f16(aC[mi], b1, acc[mi][1], 0, 0, 0);
        }
#pragma unroll
        for (int mi = 0; mi < 3; mi++) aC[mi] = aN[mi];
    }
    __syncthreads();   // all waves done reading wl before aliasing as hh

    float* hh = (float*)wl;    // [192][33]
#pragma unroll
    for (int mi = 0; mi < 3; mi++) {
        int ob = (mt0 + mi) * 16 + q * 4;
#pragma unroll
        for (int ni = 0; ni < 2; ni++)
#pragma unroll
            for (int rr = 0; rr < 4; rr++) {
                int o = ob + rr;
                hh[o * 33 + ni * 16 + n] = acc[mi][ni][rr] + biases[282 + o];
            }
    }
    __syncthreads();

    // gates: cc on lanes -> coalesced i2hT/xph reads; nh written back into hh
#pragma unroll 1
    for (int j = 0; j < 8; j++) {
        int i = t + 256 * j;
        int cc = i & 63, p = i >> 6;
        float h0v = hh[cc * 33 + p];
        float h1v = hh[(64 + cc) * 33 + p];
        float h2v = hh[(128 + cc) * 33 + p];
        int pix = (b * 96 + h) * 96 + w0 + p;
        float i0 = h2f(i2hT[pix * 192 + cc]);
        float i1 = h2f(i2hT[pix * 192 + 64 + cc]);
        float i2 = h2f(i2hT[pix * 192 + 128 + cc]);
        float pv = h2f(xph[(pix << 7) + 64 + cc]);
        float rg = sigm(i0 + h0v);
        float ug = sigm(i1 + h1v);
        float nm = i2 + rg * h2v;
        nm = (nm > 0.f) ? nm : NEG * nm;
        float nh = ug * pv + (1.f - ug) * nm;
        hh[cc * 33 + p] = nh;   // row cc<64 cell (cc,p): read only by this thread above
    }
    __syncthreads();

    // write-out: p on lanes -> coalesced stores of both copies
#pragma unroll 1
    for (int j = 0; j < 8; j++) {
        int i = t + 256 * j;
        int p = i & 31, cc = i >> 5;
        float nh = hh[cc * 33 + p];
        int oidx = ((b * 64 + cc) * 96 + h) * 96 + w0 + p;
        if (flg) {
            float* of = (float*)out;
            of[oidx] = nh;
            of[oidx + 2 * 4718592] = nh;
        } else {
            u16* ob16 = (u16*)out;
            u16 v = f2b(nh);
            ob16[oidx] = v;
            ob16[oidx + 2 * 4718592] = v;
        }
    }
}

// ---------------- K5: copy m passthrough (dtype-size aware, 16B) ------------
__global__ void kcopym(const uint4* __restrict__ m, uint4* __restrict__ out,
                       const u32* __restrict__ flag)
{
    int flg = (int)flag[0];
    int n = flg ? 1179648 : 589824;   // uint4 per tensor
    int stride = gridDim.x * 256;
    for (int i = blockIdx.x * 256 + threadIdx.x; i < n; i += stride)
        out[n + i] = m[i];
}

extern "C" void kernel_launch(void* const* d_in, const int* in_sizes, int n_in,
                              void* d_out, int out_size, void* d_ws, size_t ws_size,
                              hipStream_t stream)
{
    const void* x     = d_in[0];
    const void* m     = d_in[1];
    const void* ph    = d_in[2];
    const void* w_i2h = d_in[3];
    const void* b_i2h = d_in[4];
    const void* w_i2f = d_in[5];
    const void* b_i2f = d_in[6];
    const void* w_h2f = d_in[7];
    const void* b_h2f = d_in[8];
    const void* w_fl  = d_in[9];
    const void* b_fl  = d_in[10];
    const void* w_ret = d_in[11];
    const void* b_ret = d_in[12];

    char* ws = (char*)d_ws;
    u32*    flag   = (u32*)  (ws + 0);
    u16*    wiA    = (u16*)  (ws + 64);
    u16*    wfA    = (u16*)  (ws + 221248);
    u16*    wlA    = (u16*)  (ws + 426048);
    u16*    wretA  = (u16*)  (ws + 477248);
    float*  biases = (float*)(ws + 796736);
    u16*    xph    = (u16*)  (ws + 798784);
    u16*    i2hT   = (u16*)  (ws + 19673152);
    u16*    fT     = (u16*)  (ws + 47984704);
    float*  flows  = (float*)(ws + 52703296);
    if (ws_size < WS_NEED) return;  // diagnostic signature: absmax == max|ref|

    kdetect<<<1, 256, 0, stream>>>((const u16*)x, flag);
    kprep<<<624, 256, 0, stream>>>(w_i2h, w_i2f, w_h2f, w_fl, w_ret,
                                   b_i2h, b_i2f, b_h2f, b_fl, b_ret,
                                   wiA, wfA, wlA, wretA, biases, flag);
    kxph<<<dim3(96, 8), 256, 0, stream>>>(x, ph, xph, flag);
    k_convs<<<576, 256, 0, stream>>>(xph, wiA, wfA, biases, i2hT, fT);
    k_flows<<<1152, 256, 0, stream>>>(fT, wlA, biases, flows);
    k_fused<<<2304, 256, 0, stream>>>(flows, xph, i2hT, wretA, biases,
                                      d_out, flag);
    kcopym<<<2048, 256, 0, stream>>>((const uint4*)m, (uint4*)d_out, flag);
}